// Round 21
// baseline (227.186 us; speedup 1.0000x reference)
//
#include <hip/hip_runtime.h>
#include <math.h>

#define BB 4
#define SS 2048
#define NN 4096
#define DD 256
#define ROWS (BB*SS)        // 8192
#define TOPN 5
#define BM 128
#define BN 64
#define BK 64
#define NRB (ROWS/BM)       // 64 row blocks
#define NCBK (NN/BN)        // 64 col blocks
#define NWG (NRB*NCBK)      // 4096
#define NCAND 16
#define PROJ_BLKS ((ROWS/64)*(DD/64))   // 512
#define PREP_BLKS ((2*BB*NN)/4)         // 8192

typedef short bf16x8 __attribute__((ext_vector_type(8)));
typedef float f32x4  __attribute__((ext_vector_type(4)));
typedef unsigned short u16x4 __attribute__((ext_vector_type(4)));

__device__ inline unsigned short f2bf(float f) {
    unsigned int u = __float_as_uint(f);
    unsigned int r = u + 0x7fffu + ((u >> 16) & 1u);   // RNE
    return (unsigned short)(r >> 16);
}

// pack 2 floats -> 2 fp16 (RTZ) in one uint via v_cvt_pkrtz_f16_f32.
// RTZ is monotone on the stored fp32 value, but the stored value carries
// bf16-GEMM error (~6.6e-3 at 6 sigma) -> threshold gate needs a margin.
__device__ inline unsigned pk2h(float a, float b) {
    typedef __fp16 h2 __attribute__((ext_vector_type(2)));
    h2 h = __builtin_amdgcn_cvt_pkrtz(a, b);
    return __builtin_bit_cast(unsigned, h);
}

// HBM -> LDS direct, 16 B per lane. LDS dest is wave-uniform base + lane*16.
__device__ inline void gload_lds16(const void* g, void* l) {
    __builtin_amdgcn_global_load_lds(
        (const __attribute__((address_space(1))) unsigned int*)g,
        (__attribute__((address_space(3))) unsigned int*)l, 16, 0, 0);
}

// sorted-5 insert MACROS on named scalars (NEVER a reference-param helper:
// refs defeat mem2reg -> scratch; round-6 showed 10x). Keys are fp16 bit
// patterns compared as unsigned (monotone for values >= 0).
// NCAND=16 REQUIRED with fp16 keys (round-10 tie-bucket failure at 8).
#define INS5A(vv, gg)                                                   \
    do {                                                                \
        unsigned _v = (vv); int _g = (gg);                              \
        if (_v < B4) {                                                  \
            if (_v < B3) { B4 = B3; I4 = I3;                            \
                if (_v < B2) { B3 = B2; I3 = I2;                        \
                    if (_v < B1) { B2 = B1; I2 = I1;                    \
                        if (_v < B0) { B1 = B0; I1 = I0; B0 = _v; I0 = _g; } \
                        else         { B1 = _v; I1 = _g; }              \
                    } else { B2 = _v; I2 = _g; }                        \
                } else { B3 = _v; I3 = _g; }                            \
            } else { B4 = _v; I4 = _g; }                                \
        }                                                               \
    } while (0)

#define INS5B(vv, gg)                                                   \
    do {                                                                \
        unsigned _v = (vv); int _g = (gg);                              \
        if (_v < C4) {                                                  \
            if (_v < C3) { C4 = C3; J4 = J3;                            \
                if (_v < C2) { C3 = C2; J3 = J2;                        \
                    if (_v < C1) { C2 = C1; J2 = J1;                    \
                        if (_v < C0) { C1 = C0; J1 = J0; C0 = _v; J0 = _g; } \
                        else         { C1 = _v; J1 = _g; }              \
                    } else { C2 = _v; J2 = _g; }                        \
                } else { C3 = _v; J3 = _g; }                            \
            } else { C4 = _v; J4 = _g; }                                \
        }                                                               \
    } while (0)

// ---- K1 (FUSED): proj blocks [0,512) = fp64 GEMM qp=q@Wq^T+bq;
//      prep blocks [512,8704) = ctx/mem bf16 convert + fp64/fp32 rownorm.
__global__ __launch_bounds__(256) void k_proj_prep(
    const float* __restrict__ q, const float* __restrict__ Wq,
    const float* __restrict__ bq, double* __restrict__ qp64,
    unsigned short* __restrict__ qpb,
    const float* __restrict__ ctx, const float* __restrict__ mem,
    unsigned short* __restrict__ ctxb, unsigned short* __restrict__ memb,
    double* __restrict__ c2c64, double* __restrict__ c2m64,
    float* __restrict__ c2c32, float* __restrict__ c2m32)
{
    __shared__ float As[64][65];
    __shared__ float Bs[64][65];

    if (blockIdx.x < PROJ_BLKS) {
        const int rowbase = (blockIdx.x >> 2) * 64;
        const int ebase   = (blockIdx.x & 3) * 64;
        const int t  = threadIdx.x;
        const int tx = t & 15;
        const int ty = t >> 4;

        double acc[4][4];
        #pragma unroll
        for (int i = 0; i < 4; ++i)
            #pragma unroll
            for (int j = 0; j < 4; ++j) acc[i][j] = 0.0;

        for (int k0 = 0; k0 < DD; k0 += 64) {
            #pragma unroll
            for (int i = 0; i < 4; ++i) {
                int r = ty + (i << 4);
                float4 va = *(const float4*)(q  + (size_t)(rowbase + r) * DD + k0 + (tx << 2));
                As[(tx<<2)+0][r] = va.x; As[(tx<<2)+1][r] = va.y;
                As[(tx<<2)+2][r] = va.z; As[(tx<<2)+3][r] = va.w;
                float4 vb = *(const float4*)(Wq + (size_t)(ebase + r) * DD + k0 + (tx << 2));
                Bs[(tx<<2)+0][r] = vb.x; Bs[(tx<<2)+1][r] = vb.y;
                Bs[(tx<<2)+2][r] = vb.z; Bs[(tx<<2)+3][r] = vb.w;
            }
            __syncthreads();
            #pragma unroll 4
            for (int kk = 0; kk < 64; ++kk) {
                double a[4], bb[4];
                #pragma unroll
                for (int i = 0; i < 4; ++i) a[i]  = (double)As[kk][(ty<<2)+i];
                #pragma unroll
                for (int j = 0; j < 4; ++j) bb[j] = (double)Bs[kk][(tx<<2)+j];
                #pragma unroll
                for (int i = 0; i < 4; ++i)
                    #pragma unroll
                    for (int j = 0; j < 4; ++j)
                        acc[i][j] = fma(a[i], bb[j], acc[i][j]);
            }
            __syncthreads();
        }
        #pragma unroll
        for (int i = 0; i < 4; ++i) {
            int row = rowbase + (ty << 2) + i;
            #pragma unroll
            for (int j = 0; j < 4; ++j) {
                int e = ebase + (tx << 2) + j;
                double r = acc[i][j] + (double)bq[e];
                qp64[(size_t)row * DD + e] = r;
                qpb[(size_t)row * DD + e] = f2bf((float)r);
            }
        }
    } else {
        int rid  = (blockIdx.x - PROJ_BLKS) * 4 + (threadIdx.x >> 6);
        int lane = threadIdx.x & 63;
        const float* x; unsigned short* xb; double* n64; float* n32; int row;
        if (rid < BB * NN) { x = ctx; xb = ctxb; n64 = c2c64; n32 = c2c32; row = rid; }
        else               { x = mem; xb = memb; n64 = c2m64; n32 = c2m32; row = rid - BB * NN; }

        float4 v = *(const float4*)(x + (size_t)row * DD + (lane << 2));
        u16x4 o;
        o[0] = f2bf(v.x); o[1] = f2bf(v.y); o[2] = f2bf(v.z); o[3] = f2bf(v.w);
        *(u16x4*)(xb + (size_t)row * DD + (lane << 2)) = o;
        double s = (double)v.x*(double)v.x + (double)v.y*(double)v.y
                 + (double)v.z*(double)v.z + (double)v.w*(double)v.w;
        #pragma unroll
        for (int off = 32; off; off >>= 1) s += __shfl_xor(s, off);
        if (lane == 0) { n64[row] = s; n32[row] = (float)s; }
    }
}

// ------- row stats (ONE launch): |qp|^2 (fp64) AND gate sigmoid (fp64) -----
__global__ __launch_bounds__(256) void k_row_stats(
    const double* __restrict__ qp64, const float* __restrict__ q,
    const float* __restrict__ wg, const float* __restrict__ bg,
    double* __restrict__ q264, float* __restrict__ q232,
    double* __restrict__ g64, float* __restrict__ g32)
{
    int row  = blockIdx.x * 4 + (threadIdx.x >> 6);
    int lane = threadIdx.x & 63;
    const double* p = qp64 + (size_t)row * DD + (lane << 2);
    double s = p[0]*p[0] + p[1]*p[1] + p[2]*p[2] + p[3]*p[3];
    float4 v = *(const float4*)(q  + (size_t)row * DD + (lane << 2));
    float4 w = *(const float4*)(wg + (lane << 2));
    double t = (double)v.x*(double)w.x + (double)v.y*(double)w.y
             + (double)v.z*(double)w.z + (double)v.w*(double)w.w;
    #pragma unroll
    for (int off = 32; off; off >>= 1) {
        s += __shfl_xor(s, off);
        t += __shfl_xor(t, off);
    }
    if (lane == 0) {
        q264[row] = s; q232[row] = (float)s;
        double g = 1.0 / (1.0 + exp(-(t + (double)bg[0])));
        g64[row] = g; g32[row] = (float)g;
    }
}

// ---------------- K3: bf16 MFMA distance GEMM -> packed fp16 dist ----------
// r21: A-operand direct global->register (per-fragment load = 16 rows x one
// 64B line, L2-hot panel; no LDS for A). B staging XOR-swizzled via
// pre-swizzled gload source (r3-validated math: src chunk = (s&7)^(r&7),
// read pos = k^(lane&7)) -> B ds_reads 2-way conflict (free, m136).
// LDS halves to 16 KB (B tiles only).
__global__ __launch_bounds__(256, 1) void k_dist_mfma(
    const unsigned short* __restrict__ qpb,
    const unsigned short* __restrict__ ctxb,
    const unsigned short* __restrict__ memb,
    const float* __restrict__ q2, const float* __restrict__ gate,
    const float* __restrict__ c2c, const float* __restrict__ c2m,
    unsigned* __restrict__ distP)
{
    __shared__ __attribute__((aligned(16))) char smem[16384];
    const int tid  = threadIdx.x;
    const int lane = tid & 63;
    const int wid  = tid >> 6;
    const int wr   = wid >> 1;       // wave row (0/1) -> 64-row half
    const int wc   = wid & 1;        // wave col (0/1) -> 32-col half
    // bijective XCD-chunk swizzle (NWG=4096 % 8 == 0)
    const int orig = blockIdx.x;
    const int lid  = (orig & 7) * (NWG / 8) + (orig >> 3);
    const int rowbase = (lid >> 6) * BM;   // rb = lid/64
    const int colbase = (lid & 63) * BN;   // cb = lid%64
    const int b = rowbase / SS;
    const unsigned short* cb  = ctxb + (size_t)b * NN * DD;
    const unsigned short* mbp = memb + (size_t)b * NN * DD;

    f32x4 accC[4][2], accM[4][2];
    f32x4 zz = {0.f, 0.f, 0.f, 0.f};
    #pragma unroll
    for (int i = 0; i < 4; ++i)
        #pragma unroll
        for (int j = 0; j < 2; ++j) { accC[i][j] = zz; accM[i][j] = zz; }

    // A fragment base pointers (per-lane, t/ks-invariant): lane reads row
    // (rowbase + wr*64 + f*16 + lane&15), 16 B at chunk (lane>>4); per-(t,ks)
    // offset = t*64 + ks*32 elements (compile-time -> imm offset).
    const unsigned short* aP[4];
    #pragma unroll
    for (int f = 0; f < 4; ++f)
        aP[f] = qpb + (size_t)(rowbase + wr * 64 + f * 16 + (lane & 15)) * DD
                    + ((lane >> 4) << 3);

    // B staging (gload_lds, linear dest): slot s holds tile-row r = s>>3 at
    // pos p = s&7; SOURCE chunk = p ^ (r&7) (pre-swizzled global address).
    const unsigned short* gC[2];
    const unsigned short* gM[2];
    char* lC[2];
    char* lM[2];
    #pragma unroll
    for (int i = 0; i < 2; ++i) {
        int s = i * 256 + tid;
        int r = s >> 3;
        int c = (s & 7) ^ (r & 7);
        gC[i] = cb  + (size_t)(colbase + r) * DD + c * 8;
        gM[i] = mbp + (size_t)(colbase + r) * DD + c * 8;
        lC[i] = smem + i * 4096 + wid * 1024;
        lM[i] = smem + 8192 + i * 4096 + wid * 1024;
    }

    #pragma unroll
    for (int t = 0; t < DD / BK; ++t) {
        __syncthreads();   // previous consume done
        #pragma unroll
        for (int i = 0; i < 2; ++i) {
            gload_lds16(gC[i] + t * BK, lC[i]);
            gload_lds16(gM[i] + t * BK, lM[i]);
        }
        __syncthreads();   // stage visible
        #pragma unroll
        for (int ks = 0; ks < 2; ++ks) {
            // swizzled B read: chunk k at pos k^(brow&7); brow&7 == lane&7
            const int koff = (((ks * 4 + (lane >> 4)) ^ (lane & 7)) << 4);
            bf16x8 af[4], bcf[2], bmf[2];
            #pragma unroll
            for (int f = 0; f < 4; ++f)
                af[f] = *(const bf16x8*)(aP[f] + t * 64 + ks * 32);
            #pragma unroll
            for (int f = 0; f < 2; ++f) {
                int brow = wc * 32 + f * 16 + (lane & 15);
                bcf[f] = *(const bf16x8*)(smem + brow * 128 + koff);
                bmf[f] = *(const bf16x8*)(smem + 8192 + brow * 128 + koff);
            }
            #pragma unroll
            for (int mf = 0; mf < 4; ++mf)
                #pragma unroll
                for (int nf = 0; nf < 2; ++nf) {
                    accC[mf][nf] = __builtin_amdgcn_mfma_f32_16x16x32_bf16(
                        af[mf], bcf[nf], accC[mf][nf], 0, 0, 0);
                    accM[mf][nf] = __builtin_amdgcn_mfma_f32_16x16x32_bf16(
                        af[mf], bmf[nf], accM[mf][nf], 0, 0, 0);
                }
        }
    }

    // per-lane row/col metadata (C/D map: row=(lane>>4)*4+reg, col=lane&15)
    float q2r[4][4], gr[4][4];
    #pragma unroll
    for (int mf = 0; mf < 4; ++mf)
        #pragma unroll
        for (int rg = 0; rg < 4; ++rg) {
            int r = rowbase + wr * 64 + mf * 16 + ((lane >> 4) << 2) + rg;
            q2r[mf][rg] = q2[r];
            gr[mf][rg]  = gate[r];
        }
    float ccv[2], cmv[2];
    #pragma unroll
    for (int nf = 0; nf < 2; ++nf) {
        int c = colbase + wc * 32 + nf * 16 + (lane & 15);
        ccv[nf] = c2c[b * NN + c];
        cmv[nf] = c2m[b * NN + c];
    }

    #pragma unroll
    for (int mf = 0; mf < 4; ++mf) {
        // even base row of this lane's 4-row group
        size_t p0 = (size_t)((rowbase + wr * 64 + mf * 16
                              + ((lane >> 4) << 2)) >> 1) * NN;
        #pragma unroll
        for (int nf = 0; nf < 2; ++nf) {
            int col = colbase + wc * 32 + nf * 16 + (lane & 15);
            float d[4];
            #pragma unroll
            for (int rg = 0; rg < 4; ++rg) {
                float g  = gr[mf][rg];
                float dc = sqrtf(fmaxf(q2r[mf][rg] + ccv[nf]
                                       - 2.0f * accC[mf][nf][rg], 0.f));
                float dm = sqrtf(fmaxf(q2r[mf][rg] + cmv[nf]
                                       - 2.0f * accM[mf][nf][rg], 0.f));
                d[rg] = fmaf(g, dc - dm, dm);
            }
            distP[p0 + col]      = pk2h(d[0], d[1]);
            distP[p0 + NN + col] = pk2h(d[2], d[3]);
        }
    }
}

// ---------------- K4: per-row-pair top-16 candidates + sorted fp16 vals ---
__global__ __launch_bounds__(256) void k_filter(
    const unsigned* __restrict__ distP, int* __restrict__ cand,
    unsigned short* __restrict__ cval)
{
    int pair = blockIdx.x * 4 + (threadIdx.x >> 6);
    int lane = threadIdx.x & 63;
    const unsigned* dr = distP + (size_t)pair * NN;

    unsigned B0 = 0xFFFFu, B1 = 0xFFFFu, B2 = 0xFFFFu, B3 = 0xFFFFu, B4 = 0xFFFFu;
    int I0 = 0x7fffffff, I1 = 0x7fffffff, I2 = 0x7fffffff, I3 = 0x7fffffff, I4 = 0x7fffffff;
    unsigned C0 = 0xFFFFu, C1 = 0xFFFFu, C2 = 0xFFFFu, C3 = 0xFFFFu, C4 = 0xFFFFu;
    int J0 = 0x7fffffff, J1 = 0x7fffffff, J2 = 0x7fffffff, J3 = 0x7fffffff, J4 = 0x7fffffff;

    #pragma unroll
    for (int ch = 0; ch < 16; ++ch) {
        uint4 w = *(const uint4*)(dr + ch * 256 + lane * 4);
        int base = ch * 256 + lane * 4;
        INS5A(w.x & 0xFFFFu, base + 0);  INS5B(w.x >> 16, base + 0);
        INS5A(w.y & 0xFFFFu, base + 1);  INS5B(w.y >> 16, base + 1);
        INS5A(w.z & 0xFFFFu, base + 2);  INS5B(w.z >> 16, base + 2);
        INS5A(w.w & 0xFFFFu, base + 3);  INS5B(w.w >> 16, base + 3);
    }

    // even row merge -> cand/cval[(2*pair)*NCAND + r]  (sorted by val,idx)
    #pragma unroll
    for (int r = 0; r < NCAND; ++r) {
        unsigned mv = B0; int mi = I0;
        #pragma unroll
        for (int off = 1; off < 64; off <<= 1) {
            unsigned ov = __shfl_xor(mv, off);
            int      oi = __shfl_xor(mi, off);
            if (ov < mv || (ov == mv && oi < mi)) { mv = ov; mi = oi; }
        }
        if (B0 == mv && I0 == mi) {
            B0 = B1; I0 = I1; B1 = B2; I1 = I2; B2 = B3; I2 = I3;
            B3 = B4; I3 = I4; B4 = 0xFFFFu; I4 = 0x7fffffff;
        }
        if (lane == 0) {
            cand[(size_t)(2 * pair) * NCAND + r] = mi;
            cval[(size_t)(2 * pair) * NCAND + r] = (unsigned short)mv;
        }
    }
    // odd row merge -> cand/cval[(2*pair+1)*NCAND + r]
    #pragma unroll
    for (int r = 0; r < NCAND; ++r) {
        unsigned mv = C0; int mi = J0;
        #pragma unroll
        for (int off = 1; off < 64; off <<= 1) {
            unsigned ov = __shfl_xor(mv, off);
            int      oi = __shfl_xor(mi, off);
            if (ov < mv || (ov == mv && oi < mi)) { mv = ov; mi = oi; }
        }
        if (C0 == mv && J0 == mi) {
            C0 = C1; J0 = J1; C1 = C2; J1 = J2; C2 = C3; J2 = J3;
            C3 = C4; J3 = J4; C4 = 0xFFFFu; J4 = 0x7fffffff;
        }
        if (lane == 0) {
            cand[(size_t)(2 * pair + 1) * NCAND + r] = mi;
            cval[(size_t)(2 * pair + 1) * NCAND + r] = (unsigned short)mv;
        }
    }
}

// ------- K5: fp64 exact rescore, MARGIN-gated, final top-5; 4 rows/blk ----
// thresh = cv[4] + 4 fp16 ulps (r17-verified margin).
__global__ __launch_bounds__(256) void k_rescore(
    const double* __restrict__ qp64, const float* __restrict__ ctx,
    const float* __restrict__ mem, const double* __restrict__ q2,
    const double* __restrict__ gate, const double* __restrict__ c2c,
    const double* __restrict__ c2m, const int* __restrict__ cand,
    const unsigned short* __restrict__ cval, float* __restrict__ out)
{
    __shared__ double sval[4][NCAND];
    __shared__ int    sidx[4][NCAND];
    const int w    = threadIdx.x >> 6;
    const int row  = blockIdx.x * 4 + w;
    const int lane = threadIdx.x & 63;
    const int b = row / SS;

    const double* qr = qp64 + (size_t)row * DD + (lane << 2);
    double a0 = qr[0], a1 = qr[1], a2 = qr[2], a3 = qr[3];
    double q2r = q2[row], g = gate[row];

    if (lane == 0) {
        #pragma unroll
        for (int c = 0; c < NCAND; ++c) { sval[w][c] = INFINITY; sidx[w][c] = 0x7fffffff; }
    }
    const unsigned short* cv = cval + (size_t)row * NCAND;
    const unsigned thresh = (unsigned)cv[4] + 4;   // +4 fp16 ulps margin

    for (int c = 0; c < NCAND; ++c) {
        if ((unsigned)cv[c] > thresh) break;   // uniform: same addr all lanes
        int idx = cand[(size_t)row * NCAND + c];
        const float4 vc = *(const float4*)(ctx + ((size_t)b * NN + idx) * DD + (lane << 2));
        const float4 vm = *(const float4*)(mem + ((size_t)b * NN + idx) * DD + (lane << 2));
        double sc = a0*(double)vc.x + a1*(double)vc.y + a2*(double)vc.z + a3*(double)vc.w;
        double sm = a0*(double)vm.x + a1*(double)vm.y + a2*(double)vm.z + a3*(double)vm.w;
        #pragma unroll
        for (int off = 32; off; off >>= 1) {
            sc += __shfl_xor(sc, off);
            sm += __shfl_xor(sm, off);
        }
        if (lane == 0) {
            double dc = sqrt(fmax(q2r + c2c[(size_t)b * NN + idx] - 2.0 * sc, 0.0));
            double dm = sqrt(fmax(q2r + c2m[(size_t)b * NN + idx] - 2.0 * sm, 0.0));
            sval[w][c] = g * dc + (1.0 - g) * dm;
            sidx[w][c] = idx;
        }
    }
    // per-wave private LDS rows written and read by the same lane; no barrier
    if (lane == 0) {
        #pragma unroll
        for (int r = 0; r < TOPN; ++r) {
            double bv = sval[w][0]; int bi = sidx[w][0]; int bp = 0;
            for (int c = 1; c < NCAND; ++c) {
                double v = sval[w][c]; int ii = sidx[w][c];
                if (v < bv || (v == bv && ii < bi)) { bv = v; bi = ii; bp = c; }
            }
            sval[w][bp] = INFINITY; sidx[w][bp] = 0x7fffffff;
            out[(size_t)row * TOPN + r] = (float)bv;
            out[(size_t)ROWS * TOPN + (size_t)row * TOPN + r] = (float)bi;
        }
    }
}

extern "C" void kernel_launch(void* const* d_in, const int* in_sizes, int n_in,
                              void* d_out, int out_size, void* d_ws, size_t ws_size,
                              hipStream_t stream)
{
    const float* q   = (const float*)d_in[0];
    const float* ctx = (const float*)d_in[1];
    const float* mem = (const float*)d_in[2];
    const float* Wq  = (const float*)d_in[3];
    const float* bq  = (const float*)d_in[4];
    const float* wg  = (const float*)d_in[5];
    const float* bg  = (const float*)d_in[6];
    float* out = (float*)d_out;

    char* ws = (char*)d_ws;
    double* qp64  = (double*)ws;  ws += (size_t)ROWS * DD * 8;        // 16 MB
    double* q264  = (double*)ws;  ws += (size_t)ROWS * 8;
    double* g64   = (double*)ws;  ws += (size_t)ROWS * 8;
    double* c2c64 = (double*)ws;  ws += (size_t)BB * NN * 8;
    double* c2m64 = (double*)ws;  ws += (size_t)BB * NN * 8;
    unsigned short* qpb  = (unsigned short*)ws; ws += (size_t)ROWS * DD * 2;    // 4 MB
    unsigned short* ctxb = (unsigned short*)ws; ws += (size_t)BB * NN * DD * 2; // 8 MB
    unsigned short* memb = (unsigned short*)ws; ws += (size_t)BB * NN * DD * 2; // 8 MB
    float*  q232  = (float*)ws;   ws += (size_t)ROWS * 4;
    float*  g32   = (float*)ws;   ws += (size_t)ROWS * 4;
    float*  c2c32 = (float*)ws;   ws += (size_t)BB * NN * 4;
    float*  c2m32 = (float*)ws;   ws += (size_t)BB * NN * 4;
    unsigned* distP = (unsigned*)ws; ws += (size_t)(ROWS / 2) * NN * 4;  // 67 MB
    int*    cand  = (int*)ws;     ws += (size_t)ROWS * NCAND * 4;
    unsigned short* cval = (unsigned short*)ws; ws += (size_t)ROWS * NCAND * 2;

    k_proj_prep<<<PROJ_BLKS + PREP_BLKS, 256, 0, stream>>>(
        q, Wq, bq, qp64, qpb, ctx, mem, ctxb, memb,
        c2c64, c2m64, c2c32, c2m32);
    k_row_stats<<<ROWS/4, 256, 0, stream>>>(qp64, q, wg, bg,
                                            q264, q232, g64, g32);
    k_dist_mfma<<<NWG, 256, 0, stream>>>(
        qpb, ctxb, memb, q232, g32, c2c32, c2m32, distP);
    k_filter<<<(ROWS/2)/4, 256, 0, stream>>>(distP, cand, cval);
    k_rescore<<<ROWS/4, 256, 0, stream>>>(qp64, ctx, mem, q264, g64,
                                          c2c64, c2m64, cand, cval, out);
}

// Round 22
// 198.641 us; speedup vs baseline: 1.1437x; 1.1437x over previous
//
#include <hip/hip_runtime.h>
#include <math.h>

#define BB 4
#define SS 2048
#define NN 4096
#define DD 256
#define ROWS (BB*SS)        // 8192
#define TOPN 5
#define BM 128
#define BN 64
#define BK 64
#define NRB (ROWS/BM)       // 64 row blocks
#define NCBK (NN/BN)        // 64 col blocks
#define NWG (NRB*NCBK)      // 4096
#define NCAND 16
#define PROJ_BLKS ((ROWS/64)*(DD/64))   // 512
#define PREP_BLKS ((2*BB*NN)/4)         // 8192

typedef short bf16x8 __attribute__((ext_vector_type(8)));
typedef float f32x4  __attribute__((ext_vector_type(4)));
typedef unsigned short u16x4 __attribute__((ext_vector_type(4)));

__device__ inline unsigned short f2bf(float f) {
    unsigned int u = __float_as_uint(f);
    unsigned int r = u + 0x7fffu + ((u >> 16) & 1u);   // RNE
    return (unsigned short)(r >> 16);
}

// pack 2 floats -> 2 fp16 (RTZ) in one uint via v_cvt_pkrtz_f16_f32.
// RTZ is monotone on the stored fp32 value, but the stored value carries
// bf16-GEMM error (~6.6e-3 at 6 sigma) -> threshold gate needs a margin.
__device__ inline unsigned pk2h(float a, float b) {
    typedef __fp16 h2 __attribute__((ext_vector_type(2)));
    h2 h = __builtin_amdgcn_cvt_pkrtz(a, b);
    return __builtin_bit_cast(unsigned, h);
}

// HBM -> LDS direct, 16 B per lane. LDS dest is wave-uniform base + lane*16.
__device__ inline void gload_lds16(const void* g, void* l) {
    __builtin_amdgcn_global_load_lds(
        (const __attribute__((address_space(1))) unsigned int*)g,
        (__attribute__((address_space(3))) unsigned int*)l, 16, 0, 0);
}

// sorted-5 insert MACROS on named scalars (NEVER a reference-param helper:
// refs defeat mem2reg -> scratch; round-6 showed 10x). Keys are fp16 bit
// patterns compared as unsigned (monotone for values >= 0).
// NCAND=16 REQUIRED with fp16 keys (round-10 tie-bucket failure at 8).
#define INS5A(vv, gg)                                                   \
    do {                                                                \
        unsigned _v = (vv); int _g = (gg);                              \
        if (_v < B4) {                                                  \
            if (_v < B3) { B4 = B3; I4 = I3;                            \
                if (_v < B2) { B3 = B2; I3 = I2;                        \
                    if (_v < B1) { B2 = B1; I2 = I1;                    \
                        if (_v < B0) { B1 = B0; I1 = I0; B0 = _v; I0 = _g; } \
                        else         { B1 = _v; I1 = _g; }              \
                    } else { B2 = _v; I2 = _g; }                        \
                } else { B3 = _v; I3 = _g; }                            \
            } else { B4 = _v; I4 = _g; }                                \
        }                                                               \
    } while (0)

#define INS5B(vv, gg)                                                   \
    do {                                                                \
        unsigned _v = (vv); int _g = (gg);                              \
        if (_v < C4) {                                                  \
            if (_v < C3) { C4 = C3; J4 = J3;                            \
                if (_v < C2) { C3 = C2; J3 = J2;                        \
                    if (_v < C1) { C2 = C1; J2 = J1;                    \
                        if (_v < C0) { C1 = C0; J1 = J0; C0 = _v; J0 = _g; } \
                        else         { C1 = _v; J1 = _g; }              \
                    } else { C2 = _v; J2 = _g; }                        \
                } else { C3 = _v; J3 = _g; }                            \
            } else { C4 = _v; J4 = _g; }                                \
        }                                                               \
    } while (0)

// ---- K1 (FUSED): proj blocks [0,512) = fp64 GEMM qp=q@Wq^T+bq;
//      prep blocks [512,8704) = ctx/mem bf16 convert + fp64/fp32 rownorm.
__global__ __launch_bounds__(256) void k_proj_prep(
    const float* __restrict__ q, const float* __restrict__ Wq,
    const float* __restrict__ bq, double* __restrict__ qp64,
    unsigned short* __restrict__ qpb,
    const float* __restrict__ ctx, const float* __restrict__ mem,
    unsigned short* __restrict__ ctxb, unsigned short* __restrict__ memb,
    double* __restrict__ c2c64, double* __restrict__ c2m64,
    float* __restrict__ c2c32, float* __restrict__ c2m32)
{
    __shared__ float As[64][65];
    __shared__ float Bs[64][65];

    if (blockIdx.x < PROJ_BLKS) {
        const int rowbase = (blockIdx.x >> 2) * 64;
        const int ebase   = (blockIdx.x & 3) * 64;
        const int t  = threadIdx.x;
        const int tx = t & 15;
        const int ty = t >> 4;

        double acc[4][4];
        #pragma unroll
        for (int i = 0; i < 4; ++i)
            #pragma unroll
            for (int j = 0; j < 4; ++j) acc[i][j] = 0.0;

        for (int k0 = 0; k0 < DD; k0 += 64) {
            #pragma unroll
            for (int i = 0; i < 4; ++i) {
                int r = ty + (i << 4);
                float4 va = *(const float4*)(q  + (size_t)(rowbase + r) * DD + k0 + (tx << 2));
                As[(tx<<2)+0][r] = va.x; As[(tx<<2)+1][r] = va.y;
                As[(tx<<2)+2][r] = va.z; As[(tx<<2)+3][r] = va.w;
                float4 vb = *(const float4*)(Wq + (size_t)(ebase + r) * DD + k0 + (tx << 2));
                Bs[(tx<<2)+0][r] = vb.x; Bs[(tx<<2)+1][r] = vb.y;
                Bs[(tx<<2)+2][r] = vb.z; Bs[(tx<<2)+3][r] = vb.w;
            }
            __syncthreads();
            #pragma unroll 4
            for (int kk = 0; kk < 64; ++kk) {
                double a[4], bb[4];
                #pragma unroll
                for (int i = 0; i < 4; ++i) a[i]  = (double)As[kk][(ty<<2)+i];
                #pragma unroll
                for (int j = 0; j < 4; ++j) bb[j] = (double)Bs[kk][(tx<<2)+j];
                #pragma unroll
                for (int i = 0; i < 4; ++i)
                    #pragma unroll
                    for (int j = 0; j < 4; ++j)
                        acc[i][j] = fma(a[i], bb[j], acc[i][j]);
            }
            __syncthreads();
        }
        #pragma unroll
        for (int i = 0; i < 4; ++i) {
            int row = rowbase + (ty << 2) + i;
            #pragma unroll
            for (int j = 0; j < 4; ++j) {
                int e = ebase + (tx << 2) + j;
                double r = acc[i][j] + (double)bq[e];
                qp64[(size_t)row * DD + e] = r;
                qpb[(size_t)row * DD + e] = f2bf((float)r);
            }
        }
    } else {
        int rid  = (blockIdx.x - PROJ_BLKS) * 4 + (threadIdx.x >> 6);
        int lane = threadIdx.x & 63;
        const float* x; unsigned short* xb; double* n64; float* n32; int row;
        if (rid < BB * NN) { x = ctx; xb = ctxb; n64 = c2c64; n32 = c2c32; row = rid; }
        else               { x = mem; xb = memb; n64 = c2m64; n32 = c2m32; row = rid - BB * NN; }

        float4 v = *(const float4*)(x + (size_t)row * DD + (lane << 2));
        u16x4 o;
        o[0] = f2bf(v.x); o[1] = f2bf(v.y); o[2] = f2bf(v.z); o[3] = f2bf(v.w);
        *(u16x4*)(xb + (size_t)row * DD + (lane << 2)) = o;
        double s = (double)v.x*(double)v.x + (double)v.y*(double)v.y
                 + (double)v.z*(double)v.z + (double)v.w*(double)v.w;
        #pragma unroll
        for (int off = 32; off; off >>= 1) s += __shfl_xor(s, off);
        if (lane == 0) { n64[row] = s; n32[row] = (float)s; }
    }
}

// ------- row stats (ONE launch): |qp|^2 (fp64) AND gate sigmoid (fp64) -----
__global__ __launch_bounds__(256) void k_row_stats(
    const double* __restrict__ qp64, const float* __restrict__ q,
    const float* __restrict__ wg, const float* __restrict__ bg,
    double* __restrict__ q264, float* __restrict__ q232,
    double* __restrict__ g64, float* __restrict__ g32)
{
    int row  = blockIdx.x * 4 + (threadIdx.x >> 6);
    int lane = threadIdx.x & 63;
    const double* p = qp64 + (size_t)row * DD + (lane << 2);
    double s = p[0]*p[0] + p[1]*p[1] + p[2]*p[2] + p[3]*p[3];
    float4 v = *(const float4*)(q  + (size_t)row * DD + (lane << 2));
    float4 w = *(const float4*)(wg + (lane << 2));
    double t = (double)v.x*(double)w.x + (double)v.y*(double)w.y
             + (double)v.z*(double)w.z + (double)v.w*(double)w.w;
    #pragma unroll
    for (int off = 32; off; off >>= 1) {
        s += __shfl_xor(s, off);
        t += __shfl_xor(t, off);
    }
    if (lane == 0) {
        q264[row] = s; q232[row] = (float)s;
        double g = 1.0 / (1.0 + exp(-(t + (double)bg[0])));
        g64[row] = g; g32[row] = (float)g;
    }
}

// ---------------- K3: bf16 MFMA distance GEMM -> packed fp16 dist ----------
// r22 = r20 structure (A,B,B' staged via gload_lds, 32 KB LDS) + the
// r21-validated XOR swizzle on ALL tiles: pre-swizzled global source
// (chunk = (s&7)^(r&7), linear LDS dest) + swizzled read (pos = k^(row&7);
// row&7 == lane&7 for both A and B fragments). Conflicts: 16-way -> 0
// (r21 measured 1.26e7 -> 0 with this exact math).
__global__ __launch_bounds__(256, 1) void k_dist_mfma(
    const unsigned short* __restrict__ qpb,
    const unsigned short* __restrict__ ctxb,
    const unsigned short* __restrict__ memb,
    const float* __restrict__ q2, const float* __restrict__ gate,
    const float* __restrict__ c2c, const float* __restrict__ c2m,
    unsigned* __restrict__ distP)
{
    __shared__ __attribute__((aligned(16))) char smem[32768];
    const int tid  = threadIdx.x;
    const int lane = tid & 63;
    const int wid  = tid >> 6;
    const int wr   = wid >> 1;       // wave row (0/1) -> 64-row half
    const int wc   = wid & 1;        // wave col (0/1) -> 32-col half
    // bijective XCD-chunk swizzle (NWG=4096 % 8 == 0)
    const int orig = blockIdx.x;
    const int lid  = (orig & 7) * (NWG / 8) + (orig >> 3);
    const int rowbase = (lid >> 6) * BM;   // rb = lid/64
    const int colbase = (lid & 63) * BN;   // cb = lid%64
    const int b = rowbase / SS;
    const unsigned short* cb  = ctxb + (size_t)b * NN * DD;
    const unsigned short* mbp = memb + (size_t)b * NN * DD;

    f32x4 accC[4][2], accM[4][2];
    f32x4 zz = {0.f, 0.f, 0.f, 0.f};
    #pragma unroll
    for (int i = 0; i < 4; ++i)
        #pragma unroll
        for (int j = 0; j < 2; ++j) { accC[i][j] = zz; accM[i][j] = zz; }

    // staging: slot s -> LDS linear (row r = s>>3, pos p = s&7);
    // SOURCE chunk = p ^ (r&7)  (pre-swizzled global address, rule #21)
    const unsigned short* gA[4];
    char* lA[4];
    #pragma unroll
    for (int i = 0; i < 4; ++i) {
        int s = i * 256 + tid;
        int r = s >> 3;
        int c = (s & 7) ^ (r & 7);
        gA[i] = qpb + (size_t)(rowbase + r) * DD + c * 8;
        lA[i] = smem + i * 4096 + wid * 1024;
    }
    const unsigned short* gC[2];
    const unsigned short* gM[2];
    char* lC[2];
    char* lM[2];
    #pragma unroll
    for (int i = 0; i < 2; ++i) {
        int s = i * 256 + tid;
        int r = s >> 3;
        int c = (s & 7) ^ (r & 7);
        gC[i] = cb  + (size_t)(colbase + r) * DD + c * 8;
        gM[i] = mbp + (size_t)(colbase + r) * DD + c * 8;
        lC[i] = smem + 16384 + i * 4096 + wid * 1024;
        lM[i] = smem + 24576 + i * 4096 + wid * 1024;
    }

    #pragma unroll
    for (int t = 0; t < DD / BK; ++t) {
        __syncthreads();   // previous consume done
        #pragma unroll
        for (int i = 0; i < 4; ++i) gload_lds16(gA[i] + t * BK, lA[i]);
        #pragma unroll
        for (int i = 0; i < 2; ++i) {
            gload_lds16(gC[i] + t * BK, lC[i]);
            gload_lds16(gM[i] + t * BK, lM[i]);
        }
        __syncthreads();   // stage visible
        #pragma unroll
        for (int ks = 0; ks < 2; ++ks) {
            // swizzled read: chunk k stored at pos k^(row&7); row&7 == lane&7
            const int koff = (((ks * 4 + (lane >> 4)) ^ (lane & 7)) << 4);
            bf16x8 af[4], bcf[2], bmf[2];
            #pragma unroll
            for (int f = 0; f < 4; ++f) {
                int arow = wr * 64 + f * 16 + (lane & 15);
                af[f] = *(const bf16x8*)(smem + arow * 128 + koff);
            }
            #pragma unroll
            for (int f = 0; f < 2; ++f) {
                int brow = wc * 32 + f * 16 + (lane & 15);
                bcf[f] = *(const bf16x8*)(smem + 16384 + brow * 128 + koff);
                bmf[f] = *(const bf16x8*)(smem + 24576 + brow * 128 + koff);
            }
            #pragma unroll
            for (int mf = 0; mf < 4; ++mf)
                #pragma unroll
                for (int nf = 0; nf < 2; ++nf) {
                    accC[mf][nf] = __builtin_amdgcn_mfma_f32_16x16x32_bf16(
                        af[mf], bcf[nf], accC[mf][nf], 0, 0, 0);
                    accM[mf][nf] = __builtin_amdgcn_mfma_f32_16x16x32_bf16(
                        af[mf], bmf[nf], accM[mf][nf], 0, 0, 0);
                }
        }
    }

    // per-lane row/col metadata (C/D map: row=(lane>>4)*4+reg, col=lane&15)
    float q2r[4][4], gr[4][4];
    #pragma unroll
    for (int mf = 0; mf < 4; ++mf)
        #pragma unroll
        for (int rg = 0; rg < 4; ++rg) {
            int r = rowbase + wr * 64 + mf * 16 + ((lane >> 4) << 2) + rg;
            q2r[mf][rg] = q2[r];
            gr[mf][rg]  = gate[r];
        }
    float ccv[2], cmv[2];
    #pragma unroll
    for (int nf = 0; nf < 2; ++nf) {
        int c = colbase + wc * 32 + nf * 16 + (lane & 15);
        ccv[nf] = c2c[b * NN + c];
        cmv[nf] = c2m[b * NN + c];
    }

    #pragma unroll
    for (int mf = 0; mf < 4; ++mf) {
        // even base row of this lane's 4-row group
        size_t p0 = (size_t)((rowbase + wr * 64 + mf * 16
                              + ((lane >> 4) << 2)) >> 1) * NN;
        #pragma unroll
        for (int nf = 0; nf < 2; ++nf) {
            int col = colbase + wc * 32 + nf * 16 + (lane & 15);
            float d[4];
            #pragma unroll
            for (int rg = 0; rg < 4; ++rg) {
                float g  = gr[mf][rg];
                float dc = sqrtf(fmaxf(q2r[mf][rg] + ccv[nf]
                                       - 2.0f * accC[mf][nf][rg], 0.f));
                float dm = sqrtf(fmaxf(q2r[mf][rg] + cmv[nf]
                                       - 2.0f * accM[mf][nf][rg], 0.f));
                d[rg] = fmaf(g, dc - dm, dm);
            }
            distP[p0 + col]      = pk2h(d[0], d[1]);
            distP[p0 + NN + col] = pk2h(d[2], d[3]);
        }
    }
}

// ---------------- K4: per-row-pair top-16 candidates + sorted fp16 vals ---
__global__ __launch_bounds__(256) void k_filter(
    const unsigned* __restrict__ distP, int* __restrict__ cand,
    unsigned short* __restrict__ cval)
{
    int pair = blockIdx.x * 4 + (threadIdx.x >> 6);
    int lane = threadIdx.x & 63;
    const unsigned* dr = distP + (size_t)pair * NN;

    unsigned B0 = 0xFFFFu, B1 = 0xFFFFu, B2 = 0xFFFFu, B3 = 0xFFFFu, B4 = 0xFFFFu;
    int I0 = 0x7fffffff, I1 = 0x7fffffff, I2 = 0x7fffffff, I3 = 0x7fffffff, I4 = 0x7fffffff;
    unsigned C0 = 0xFFFFu, C1 = 0xFFFFu, C2 = 0xFFFFu, C3 = 0xFFFFu, C4 = 0xFFFFu;
    int J0 = 0x7fffffff, J1 = 0x7fffffff, J2 = 0x7fffffff, J3 = 0x7fffffff, J4 = 0x7fffffff;

    #pragma unroll
    for (int ch = 0; ch < 16; ++ch) {
        uint4 w = *(const uint4*)(dr + ch * 256 + lane * 4);
        int base = ch * 256 + lane * 4;
        INS5A(w.x & 0xFFFFu, base + 0);  INS5B(w.x >> 16, base + 0);
        INS5A(w.y & 0xFFFFu, base + 1);  INS5B(w.y >> 16, base + 1);
        INS5A(w.z & 0xFFFFu, base + 2);  INS5B(w.z >> 16, base + 2);
        INS5A(w.w & 0xFFFFu, base + 3);  INS5B(w.w >> 16, base + 3);
    }

    // even row merge -> cand/cval[(2*pair)*NCAND + r]  (sorted by val,idx)
    #pragma unroll
    for (int r = 0; r < NCAND; ++r) {
        unsigned mv = B0; int mi = I0;
        #pragma unroll
        for (int off = 1; off < 64; off <<= 1) {
            unsigned ov = __shfl_xor(mv, off);
            int      oi = __shfl_xor(mi, off);
            if (ov < mv || (ov == mv && oi < mi)) { mv = ov; mi = oi; }
        }
        if (B0 == mv && I0 == mi) {
            B0 = B1; I0 = I1; B1 = B2; I1 = I2; B2 = B3; I2 = I3;
            B3 = B4; I3 = I4; B4 = 0xFFFFu; I4 = 0x7fffffff;
        }
        if (lane == 0) {
            cand[(size_t)(2 * pair) * NCAND + r] = mi;
            cval[(size_t)(2 * pair) * NCAND + r] = (unsigned short)mv;
        }
    }
    // odd row merge -> cand/cval[(2*pair+1)*NCAND + r]
    #pragma unroll
    for (int r = 0; r < NCAND; ++r) {
        unsigned mv = C0; int mi = J0;
        #pragma unroll
        for (int off = 1; off < 64; off <<= 1) {
            unsigned ov = __shfl_xor(mv, off);
            int      oi = __shfl_xor(mi, off);
            if (ov < mv || (ov == mv && oi < mi)) { mv = ov; mi = oi; }
        }
        if (C0 == mv && J0 == mi) {
            C0 = C1; J0 = J1; C1 = C2; J1 = J2; C2 = C3; J2 = J3;
            C3 = C4; J3 = J4; C4 = 0xFFFFu; J4 = 0x7fffffff;
        }
        if (lane == 0) {
            cand[(size_t)(2 * pair + 1) * NCAND + r] = mi;
            cval[(size_t)(2 * pair + 1) * NCAND + r] = (unsigned short)mv;
        }
    }
}

// ------- K5: fp64 exact rescore, MARGIN-gated, final top-5; 4 rows/blk ----
// thresh = cv[4] + 4 fp16 ulps (r17-verified margin).
__global__ __launch_bounds__(256) void k_rescore(
    const double* __restrict__ qp64, const float* __restrict__ ctx,
    const float* __restrict__ mem, const double* __restrict__ q2,
    const double* __restrict__ gate, const double* __restrict__ c2c,
    const double* __restrict__ c2m, const int* __restrict__ cand,
    const unsigned short* __restrict__ cval, float* __restrict__ out)
{
    __shared__ double sval[4][NCAND];
    __shared__ int    sidx[4][NCAND];
    const int w    = threadIdx.x >> 6;
    const int row  = blockIdx.x * 4 + w;
    const int lane = threadIdx.x & 63;
    const int b = row / SS;

    const double* qr = qp64 + (size_t)row * DD + (lane << 2);
    double a0 = qr[0], a1 = qr[1], a2 = qr[2], a3 = qr[3];
    double q2r = q2[row], g = gate[row];

    if (lane == 0) {
        #pragma unroll
        for (int c = 0; c < NCAND; ++c) { sval[w][c] = INFINITY; sidx[w][c] = 0x7fffffff; }
    }
    const unsigned short* cv = cval + (size_t)row * NCAND;
    const unsigned thresh = (unsigned)cv[4] + 4;   // +4 fp16 ulps margin

    for (int c = 0; c < NCAND; ++c) {
        if ((unsigned)cv[c] > thresh) break;   // uniform: same addr all lanes
        int idx = cand[(size_t)row * NCAND + c];
        const float4 vc = *(const float4*)(ctx + ((size_t)b * NN + idx) * DD + (lane << 2));
        const float4 vm = *(const float4*)(mem + ((size_t)b * NN + idx) * DD + (lane << 2));
        double sc = a0*(double)vc.x + a1*(double)vc.y + a2*(double)vc.z + a3*(double)vc.w;
        double sm = a0*(double)vm.x + a1*(double)vm.y + a2*(double)vm.z + a3*(double)vm.w;
        #pragma unroll
        for (int off = 32; off; off >>= 1) {
            sc += __shfl_xor(sc, off);
            sm += __shfl_xor(sm, off);
        }
        if (lane == 0) {
            double dc = sqrt(fmax(q2r + c2c[(size_t)b * NN + idx] - 2.0 * sc, 0.0));
            double dm = sqrt(fmax(q2r + c2m[(size_t)b * NN + idx] - 2.0 * sm, 0.0));
            sval[w][c] = g * dc + (1.0 - g) * dm;
            sidx[w][c] = idx;
        }
    }
    // per-wave private LDS rows written and read by the same lane; no barrier
    if (lane == 0) {
        #pragma unroll
        for (int r = 0; r < TOPN; ++r) {
            double bv = sval[w][0]; int bi = sidx[w][0]; int bp = 0;
            for (int c = 1; c < NCAND; ++c) {
                double v = sval[w][c]; int ii = sidx[w][c];
                if (v < bv || (v == bv && ii < bi)) { bv = v; bi = ii; bp = c; }
            }
            sval[w][bp] = INFINITY; sidx[w][bp] = 0x7fffffff;
            out[(size_t)row * TOPN + r] = (float)bv;
            out[(size_t)ROWS * TOPN + (size_t)row * TOPN + r] = (float)bi;
        }
    }
}

extern "C" void kernel_launch(void* const* d_in, const int* in_sizes, int n_in,
                              void* d_out, int out_size, void* d_ws, size_t ws_size,
                              hipStream_t stream)
{
    const float* q   = (const float*)d_in[0];
    const float* ctx = (const float*)d_in[1];
    const float* mem = (const float*)d_in[2];
    const float* Wq  = (const float*)d_in[3];
    const float* bq  = (const float*)d_in[4];
    const float* wg  = (const float*)d_in[5];
    const float* bg  = (const float*)d_in[6];
    float* out = (float*)d_out;

    char* ws = (char*)d_ws;
    double* qp64  = (double*)ws;  ws += (size_t)ROWS * DD * 8;        // 16 MB
    double* q264  = (double*)ws;  ws += (size_t)ROWS * 8;
    double* g64   = (double*)ws;  ws += (size_t)ROWS * 8;
    double* c2c64 = (double*)ws;  ws += (size_t)BB * NN * 8;
    double* c2m64 = (double*)ws;  ws += (size_t)BB * NN * 8;
    unsigned short* qpb  = (unsigned short*)ws; ws += (size_t)ROWS * DD * 2;    // 4 MB
    unsigned short* ctxb = (unsigned short*)ws; ws += (size_t)BB * NN * DD * 2; // 8 MB
    unsigned short* memb = (unsigned short*)ws; ws += (size_t)BB * NN * DD * 2; // 8 MB
    float*  q232  = (float*)ws;   ws += (size_t)ROWS * 4;
    float*  g32   = (float*)ws;   ws += (size_t)ROWS * 4;
    float*  c2c32 = (float*)ws;   ws += (size_t)BB * NN * 4;
    float*  c2m32 = (float*)ws;   ws += (size_t)BB * NN * 4;
    unsigned* distP = (unsigned*)ws; ws += (size_t)(ROWS / 2) * NN * 4;  // 67 MB
    int*    cand  = (int*)ws;     ws += (size_t)ROWS * NCAND * 4;
    unsigned short* cval = (unsigned short*)ws; ws += (size_t)ROWS * NCAND * 2;

    k_proj_prep<<<PROJ_BLKS + PREP_BLKS, 256, 0, stream>>>(
        q, Wq, bq, qp64, qpb, ctx, mem, ctxb, memb,
        c2c64, c2m64, c2c32, c2m32);
    k_row_stats<<<ROWS/4, 256, 0, stream>>>(qp64, q, wg, bg,
                                            q264, q232, g64, g32);
    k_dist_mfma<<<NWG, 256, 0, stream>>>(
        qpb, ctxb, memb, q232, g32, c2c32, c2m32, distP);
    k_filter<<<(ROWS/2)/4, 256, 0, stream>>>(distP, cand, cval);
    k_rescore<<<ROWS/4, 256, 0, stream>>>(qp64, ctx, mem, q264, g64,
                                          c2c64, c2m64, cand, cval, out);
}

// Round 23
// 197.008 us; speedup vs baseline: 1.1532x; 1.0083x over previous
//
#include <hip/hip_runtime.h>
#include <math.h>

#define BB 4
#define SS 2048
#define NN 4096
#define DD 256
#define ROWS (BB*SS)        // 8192
#define TOPN 5
#define BM 64
#define BN 64
#define BK 64
#define NRB (ROWS/BM)       // 128 row blocks
#define NCBK (NN/BN)        // 64 col blocks
#define NWG (NRB*NCBK)      // 8192
#define NCAND 16
#define PROJ_BLKS ((ROWS/64)*(DD/64))   // 512
#define PREP_BLKS ((2*BB*NN)/4)         // 8192

typedef short bf16x8 __attribute__((ext_vector_type(8)));
typedef float f32x4  __attribute__((ext_vector_type(4)));
typedef unsigned short u16x4 __attribute__((ext_vector_type(4)));

__device__ inline unsigned short f2bf(float f) {
    unsigned int u = __float_as_uint(f);
    unsigned int r = u + 0x7fffu + ((u >> 16) & 1u);   // RNE
    return (unsigned short)(r >> 16);
}

// pack 2 floats -> 2 fp16 (RTZ) in one uint via v_cvt_pkrtz_f16_f32.
// RTZ is monotone on the stored fp32 value, but the stored value carries
// bf16-GEMM error (~6.6e-3 at 6 sigma) -> threshold gate needs a margin.
__device__ inline unsigned pk2h(float a, float b) {
    typedef __fp16 h2 __attribute__((ext_vector_type(2)));
    h2 h = __builtin_amdgcn_cvt_pkrtz(a, b);
    return __builtin_bit_cast(unsigned, h);
}

// HBM -> LDS direct, 16 B per lane. LDS dest is wave-uniform base + lane*16.
__device__ inline void gload_lds16(const void* g, void* l) {
    __builtin_amdgcn_global_load_lds(
        (const __attribute__((address_space(1))) unsigned int*)g,
        (__attribute__((address_space(3))) unsigned int*)l, 16, 0, 0);
}

// sorted-5 insert MACROS on named scalars (NEVER a reference-param helper:
// refs defeat mem2reg -> scratch; round-6 showed 10x). Keys are fp16 bit
// patterns compared as unsigned (monotone for values >= 0).
// NCAND=16 REQUIRED with fp16 keys (round-10 tie-bucket failure at 8).
#define INS5A(vv, gg)                                                   \
    do {                                                                \
        unsigned _v = (vv); int _g = (gg);                              \
        if (_v < B4) {                                                  \
            if (_v < B3) { B4 = B3; I4 = I3;                            \
                if (_v < B2) { B3 = B2; I3 = I2;                        \
                    if (_v < B1) { B2 = B1; I2 = I1;                    \
                        if (_v < B0) { B1 = B0; I1 = I0; B0 = _v; I0 = _g; } \
                        else         { B1 = _v; I1 = _g; }              \
                    } else { B2 = _v; I2 = _g; }                        \
                } else { B3 = _v; I3 = _g; }                            \
            } else { B4 = _v; I4 = _g; }                                \
        }                                                               \
    } while (0)

#define INS5B(vv, gg)                                                   \
    do {                                                                \
        unsigned _v = (vv); int _g = (gg);                              \
        if (_v < C4) {                                                  \
            if (_v < C3) { C4 = C3; J4 = J3;                            \
                if (_v < C2) { C3 = C2; J3 = J2;                        \
                    if (_v < C1) { C2 = C1; J2 = J1;                    \
                        if (_v < C0) { C1 = C0; J1 = J0; C0 = _v; J0 = _g; } \
                        else         { C1 = _v; J1 = _g; }              \
                    } else { C2 = _v; J2 = _g; }                        \
                } else { C3 = _v; J3 = _g; }                            \
            } else { C4 = _v; J4 = _g; }                                \
        }                                                               \
    } while (0)

// ---- K1 (FUSED): proj blocks [0,512) = fp64 GEMM qp=q@Wq^T+bq;
//      prep blocks [512,8704) = ctx/mem bf16 convert + fp64/fp32 rownorm.
__global__ __launch_bounds__(256) void k_proj_prep(
    const float* __restrict__ q, const float* __restrict__ Wq,
    const float* __restrict__ bq, double* __restrict__ qp64,
    unsigned short* __restrict__ qpb,
    const float* __restrict__ ctx, const float* __restrict__ mem,
    unsigned short* __restrict__ ctxb, unsigned short* __restrict__ memb,
    double* __restrict__ c2c64, double* __restrict__ c2m64,
    float* __restrict__ c2c32, float* __restrict__ c2m32)
{
    __shared__ float As[64][65];
    __shared__ float Bs[64][65];

    if (blockIdx.x < PROJ_BLKS) {
        const int rowbase = (blockIdx.x >> 2) * 64;
        const int ebase   = (blockIdx.x & 3) * 64;
        const int t  = threadIdx.x;
        const int tx = t & 15;
        const int ty = t >> 4;

        double acc[4][4];
        #pragma unroll
        for (int i = 0; i < 4; ++i)
            #pragma unroll
            for (int j = 0; j < 4; ++j) acc[i][j] = 0.0;

        for (int k0 = 0; k0 < DD; k0 += 64) {
            #pragma unroll
            for (int i = 0; i < 4; ++i) {
                int r = ty + (i << 4);
                float4 va = *(const float4*)(q  + (size_t)(rowbase + r) * DD + k0 + (tx << 2));
                As[(tx<<2)+0][r] = va.x; As[(tx<<2)+1][r] = va.y;
                As[(tx<<2)+2][r] = va.z; As[(tx<<2)+3][r] = va.w;
                float4 vb = *(const float4*)(Wq + (size_t)(ebase + r) * DD + k0 + (tx << 2));
                Bs[(tx<<2)+0][r] = vb.x; Bs[(tx<<2)+1][r] = vb.y;
                Bs[(tx<<2)+2][r] = vb.z; Bs[(tx<<2)+3][r] = vb.w;
            }
            __syncthreads();
            #pragma unroll 4
            for (int kk = 0; kk < 64; ++kk) {
                double a[4], bb[4];
                #pragma unroll
                for (int i = 0; i < 4; ++i) a[i]  = (double)As[kk][(ty<<2)+i];
                #pragma unroll
                for (int j = 0; j < 4; ++j) bb[j] = (double)Bs[kk][(tx<<2)+j];
                #pragma unroll
                for (int i = 0; i < 4; ++i)
                    #pragma unroll
                    for (int j = 0; j < 4; ++j)
                        acc[i][j] = fma(a[i], bb[j], acc[i][j]);
            }
            __syncthreads();
        }
        #pragma unroll
        for (int i = 0; i < 4; ++i) {
            int row = rowbase + (ty << 2) + i;
            #pragma unroll
            for (int j = 0; j < 4; ++j) {
                int e = ebase + (tx << 2) + j;
                double r = acc[i][j] + (double)bq[e];
                qp64[(size_t)row * DD + e] = r;
                qpb[(size_t)row * DD + e] = f2bf((float)r);
            }
        }
    } else {
        int rid  = (blockIdx.x - PROJ_BLKS) * 4 + (threadIdx.x >> 6);
        int lane = threadIdx.x & 63;
        const float* x; unsigned short* xb; double* n64; float* n32; int row;
        if (rid < BB * NN) { x = ctx; xb = ctxb; n64 = c2c64; n32 = c2c32; row = rid; }
        else               { x = mem; xb = memb; n64 = c2m64; n32 = c2m32; row = rid - BB * NN; }

        float4 v = *(const float4*)(x + (size_t)row * DD + (lane << 2));
        u16x4 o;
        o[0] = f2bf(v.x); o[1] = f2bf(v.y); o[2] = f2bf(v.z); o[3] = f2bf(v.w);
        *(u16x4*)(xb + (size_t)row * DD + (lane << 2)) = o;
        double s = (double)v.x*(double)v.x + (double)v.y*(double)v.y
                 + (double)v.z*(double)v.z + (double)v.w*(double)v.w;
        #pragma unroll
        for (int off = 32; off; off >>= 1) s += __shfl_xor(s, off);
        if (lane == 0) { n64[row] = s; n32[row] = (float)s; }
    }
}

// ------- row stats (ONE launch): |qp|^2 (fp64) AND gate sigmoid (fp64) -----
__global__ __launch_bounds__(256) void k_row_stats(
    const double* __restrict__ qp64, const float* __restrict__ q,
    const float* __restrict__ wg, const float* __restrict__ bg,
    double* __restrict__ q264, float* __restrict__ q232,
    double* __restrict__ g64, float* __restrict__ g32)
{
    int row  = blockIdx.x * 4 + (threadIdx.x >> 6);
    int lane = threadIdx.x & 63;
    const double* p = qp64 + (size_t)row * DD + (lane << 2);
    double s = p[0]*p[0] + p[1]*p[1] + p[2]*p[2] + p[3]*p[3];
    float4 v = *(const float4*)(q  + (size_t)row * DD + (lane << 2));
    float4 w = *(const float4*)(wg + (lane << 2));
    double t = (double)v.x*(double)w.x + (double)v.y*(double)w.y
             + (double)v.z*(double)w.z + (double)v.w*(double)w.w;
    #pragma unroll
    for (int off = 32; off; off >>= 1) {
        s += __shfl_xor(s, off);
        t += __shfl_xor(t, off);
    }
    if (lane == 0) {
        q264[row] = s; q232[row] = (float)s;
        double g = 1.0 / (1.0 + exp(-(t + (double)bg[0])));
        g64[row] = g; g32[row] = (float)g;
    }
}

// ---------------- K3: bf16 MFMA distance GEMM -> packed fp16 dist ----------
// r23: BM 128->64 (occupancy lever, r12-proven direction). Wave tile 32x32,
// acc 16 VGPR, LDS 24 KB (A 8K + Bc 8K + Bm 8K) -> 6 blocks/CU by LDS.
// XOR swizzle on all tiles (r22: conflicts == 0). Packed fp16 stores.
__global__ __launch_bounds__(256, 1) void k_dist_mfma(
    const unsigned short* __restrict__ qpb,
    const unsigned short* __restrict__ ctxb,
    const unsigned short* __restrict__ memb,
    const float* __restrict__ q2, const float* __restrict__ gate,
    const float* __restrict__ c2c, const float* __restrict__ c2m,
    unsigned* __restrict__ distP)
{
    __shared__ __attribute__((aligned(16))) char smem[24576];
    const int tid  = threadIdx.x;
    const int lane = tid & 63;
    const int wid  = tid >> 6;
    const int wr   = wid >> 1;       // wave row (0/1) -> 32-row half
    const int wc   = wid & 1;        // wave col (0/1) -> 32-col half
    // bijective XCD-chunk swizzle (NWG=8192 % 8 == 0)
    const int orig = blockIdx.x;
    const int lid  = (orig & 7) * (NWG / 8) + (orig >> 3);
    const int rowbase = (lid >> 6) * BM;   // rb = lid/64 (0..127)
    const int colbase = (lid & 63) * BN;   // cb = lid%64
    const int b = rowbase / SS;
    const unsigned short* cb  = ctxb + (size_t)b * NN * DD;
    const unsigned short* mbp = memb + (size_t)b * NN * DD;

    f32x4 accC[2][2], accM[2][2];
    f32x4 zz = {0.f, 0.f, 0.f, 0.f};
    #pragma unroll
    for (int i = 0; i < 2; ++i)
        #pragma unroll
        for (int j = 0; j < 2; ++j) { accC[i][j] = zz; accM[i][j] = zz; }

    // staging: slot s -> LDS linear (row r = s>>3, pos p = s&7);
    // SOURCE chunk = p ^ (r&7)  (pre-swizzled global address, rule #21).
    // A: 512 slots (2/thread); Bc/Bm: 512 slots (2/thread) each.
    const unsigned short* gA[2];
    char* lA[2];
    const unsigned short* gC[2];
    const unsigned short* gM[2];
    char* lC[2];
    char* lM[2];
    #pragma unroll
    for (int i = 0; i < 2; ++i) {
        int s = i * 256 + tid;
        int r = s >> 3;
        int c = (s & 7) ^ (r & 7);
        gA[i] = qpb + (size_t)(rowbase + r) * DD + c * 8;
        lA[i] = smem + i * 4096 + wid * 1024;
        gC[i] = cb  + (size_t)(colbase + r) * DD + c * 8;
        gM[i] = mbp + (size_t)(colbase + r) * DD + c * 8;
        lC[i] = smem + 8192 + i * 4096 + wid * 1024;
        lM[i] = smem + 16384 + i * 4096 + wid * 1024;
    }

    #pragma unroll
    for (int t = 0; t < DD / BK; ++t) {
        __syncthreads();   // previous consume done
        #pragma unroll
        for (int i = 0; i < 2; ++i) {
            gload_lds16(gA[i] + t * BK, lA[i]);
            gload_lds16(gC[i] + t * BK, lC[i]);
            gload_lds16(gM[i] + t * BK, lM[i]);
        }
        __syncthreads();   // stage visible
        #pragma unroll
        for (int ks = 0; ks < 2; ++ks) {
            // swizzled read: chunk k stored at pos k^(row&7); row&7 == lane&7
            const int koff = (((ks * 4 + (lane >> 4)) ^ (lane & 7)) << 4);
            bf16x8 af[2], bcf[2], bmf[2];
            #pragma unroll
            for (int f = 0; f < 2; ++f) {
                int arow = wr * 32 + f * 16 + (lane & 15);
                af[f] = *(const bf16x8*)(smem + arow * 128 + koff);
                int brow = wc * 32 + f * 16 + (lane & 15);
                bcf[f] = *(const bf16x8*)(smem + 8192 + brow * 128 + koff);
                bmf[f] = *(const bf16x8*)(smem + 16384 + brow * 128 + koff);
            }
            #pragma unroll
            for (int mf = 0; mf < 2; ++mf)
                #pragma unroll
                for (int nf = 0; nf < 2; ++nf) {
                    accC[mf][nf] = __builtin_amdgcn_mfma_f32_16x16x32_bf16(
                        af[mf], bcf[nf], accC[mf][nf], 0, 0, 0);
                    accM[mf][nf] = __builtin_amdgcn_mfma_f32_16x16x32_bf16(
                        af[mf], bmf[nf], accM[mf][nf], 0, 0, 0);
                }
        }
    }

    // per-lane row/col metadata (C/D map: row=(lane>>4)*4+reg, col=lane&15)
    float q2r[2][4], gr[2][4];
    #pragma unroll
    for (int mf = 0; mf < 2; ++mf)
        #pragma unroll
        for (int rg = 0; rg < 4; ++rg) {
            int r = rowbase + wr * 32 + mf * 16 + ((lane >> 4) << 2) + rg;
            q2r[mf][rg] = q2[r];
            gr[mf][rg]  = gate[r];
        }
    float ccv[2], cmv[2];
    #pragma unroll
    for (int nf = 0; nf < 2; ++nf) {
        int c = colbase + wc * 32 + nf * 16 + (lane & 15);
        ccv[nf] = c2c[b * NN + c];
        cmv[nf] = c2m[b * NN + c];
    }

    #pragma unroll
    for (int mf = 0; mf < 2; ++mf) {
        // even base row of this lane's 4-row group (wr*32, mf*16, (lane>>4)*4
        // all even -> pair packing stays aligned)
        size_t p0 = (size_t)((rowbase + wr * 32 + mf * 16
                              + ((lane >> 4) << 2)) >> 1) * NN;
        #pragma unroll
        for (int nf = 0; nf < 2; ++nf) {
            int col = colbase + wc * 32 + nf * 16 + (lane & 15);
            float d[4];
            #pragma unroll
            for (int rg = 0; rg < 4; ++rg) {
                float g  = gr[mf][rg];
                float dc = sqrtf(fmaxf(q2r[mf][rg] + ccv[nf]
                                       - 2.0f * accC[mf][nf][rg], 0.f));
                float dm = sqrtf(fmaxf(q2r[mf][rg] + cmv[nf]
                                       - 2.0f * accM[mf][nf][rg], 0.f));
                d[rg] = fmaf(g, dc - dm, dm);
            }
            distP[p0 + col]      = pk2h(d[0], d[1]);
            distP[p0 + NN + col] = pk2h(d[2], d[3]);
        }
    }
}

// ---------------- K4: per-row-pair top-16 candidates + sorted fp16 vals ---
__global__ __launch_bounds__(256) void k_filter(
    const unsigned* __restrict__ distP, int* __restrict__ cand,
    unsigned short* __restrict__ cval)
{
    int pair = blockIdx.x * 4 + (threadIdx.x >> 6);
    int lane = threadIdx.x & 63;
    const unsigned* dr = distP + (size_t)pair * NN;

    unsigned B0 = 0xFFFFu, B1 = 0xFFFFu, B2 = 0xFFFFu, B3 = 0xFFFFu, B4 = 0xFFFFu;
    int I0 = 0x7fffffff, I1 = 0x7fffffff, I2 = 0x7fffffff, I3 = 0x7fffffff, I4 = 0x7fffffff;
    unsigned C0 = 0xFFFFu, C1 = 0xFFFFu, C2 = 0xFFFFu, C3 = 0xFFFFu, C4 = 0xFFFFu;
    int J0 = 0x7fffffff, J1 = 0x7fffffff, J2 = 0x7fffffff, J3 = 0x7fffffff, J4 = 0x7fffffff;

    #pragma unroll
    for (int ch = 0; ch < 16; ++ch) {
        uint4 w = *(const uint4*)(dr + ch * 256 + lane * 4);
        int base = ch * 256 + lane * 4;
        INS5A(w.x & 0xFFFFu, base + 0);  INS5B(w.x >> 16, base + 0);
        INS5A(w.y & 0xFFFFu, base + 1);  INS5B(w.y >> 16, base + 1);
        INS5A(w.z & 0xFFFFu, base + 2);  INS5B(w.z >> 16, base + 2);
        INS5A(w.w & 0xFFFFu, base + 3);  INS5B(w.w >> 16, base + 3);
    }

    // even row merge -> cand/cval[(2*pair)*NCAND + r]  (sorted by val,idx)
    #pragma unroll
    for (int r = 0; r < NCAND; ++r) {
        unsigned mv = B0; int mi = I0;
        #pragma unroll
        for (int off = 1; off < 64; off <<= 1) {
            unsigned ov = __shfl_xor(mv, off);
            int      oi = __shfl_xor(mi, off);
            if (ov < mv || (ov == mv && oi < mi)) { mv = ov; mi = oi; }
        }
        if (B0 == mv && I0 == mi) {
            B0 = B1; I0 = I1; B1 = B2; I1 = I2; B2 = B3; I2 = I3;
            B3 = B4; I3 = I4; B4 = 0xFFFFu; I4 = 0x7fffffff;
        }
        if (lane == 0) {
            cand[(size_t)(2 * pair) * NCAND + r] = mi;
            cval[(size_t)(2 * pair) * NCAND + r] = (unsigned short)mv;
        }
    }
    // odd row merge -> cand/cval[(2*pair+1)*NCAND + r]
    #pragma unroll
    for (int r = 0; r < NCAND; ++r) {
        unsigned mv = C0; int mi = J0;
        #pragma unroll
        for (int off = 1; off < 64; off <<= 1) {
            unsigned ov = __shfl_xor(mv, off);
            int      oi = __shfl_xor(mi, off);
            if (ov < mv || (ov == mv && oi < mi)) { mv = ov; mi = oi; }
        }
        if (C0 == mv && J0 == mi) {
            C0 = C1; J0 = J1; C1 = C2; J1 = J2; C2 = C3; J2 = J3;
            C3 = C4; J3 = J4; C4 = 0xFFFFu; J4 = 0x7fffffff;
        }
        if (lane == 0) {
            cand[(size_t)(2 * pair + 1) * NCAND + r] = mi;
            cval[(size_t)(2 * pair + 1) * NCAND + r] = (unsigned short)mv;
        }
    }
}

// ------- K5: fp64 exact rescore, MARGIN-gated, final top-5; 4 rows/blk ----
// thresh = cv[4] + 4 fp16 ulps (r17-verified margin).
__global__ __launch_bounds__(256) void k_rescore(
    const double* __restrict__ qp64, const float* __restrict__ ctx,
    const float* __restrict__ mem, const double* __restrict__ q2,
    const double* __restrict__ gate, const double* __restrict__ c2c,
    const double* __restrict__ c2m, const int* __restrict__ cand,
    const unsigned short* __restrict__ cval, float* __restrict__ out)
{
    __shared__ double sval[4][NCAND];
    __shared__ int    sidx[4][NCAND];
    const int w    = threadIdx.x >> 6;
    const int row  = blockIdx.x * 4 + w;
    const int lane = threadIdx.x & 63;
    const int b = row / SS;

    const double* qr = qp64 + (size_t)row * DD + (lane << 2);
    double a0 = qr[0], a1 = qr[1], a2 = qr[2], a3 = qr[3];
    double q2r = q2[row], g = gate[row];

    if (lane == 0) {
        #pragma unroll
        for (int c = 0; c < NCAND; ++c) { sval[w][c] = INFINITY; sidx[w][c] = 0x7fffffff; }
    }
    const unsigned short* cv = cval + (size_t)row * NCAND;
    const unsigned thresh = (unsigned)cv[4] + 4;   // +4 fp16 ulps margin

    for (int c = 0; c < NCAND; ++c) {
        if ((unsigned)cv[c] > thresh) break;   // uniform: same addr all lanes
        int idx = cand[(size_t)row * NCAND + c];
        const float4 vc = *(const float4*)(ctx + ((size_t)b * NN + idx) * DD + (lane << 2));
        const float4 vm = *(const float4*)(mem + ((size_t)b * NN + idx) * DD + (lane << 2));
        double sc = a0*(double)vc.x + a1*(double)vc.y + a2*(double)vc.z + a3*(double)vc.w;
        double sm = a0*(double)vm.x + a1*(double)vm.y + a2*(double)vm.z + a3*(double)vm.w;
        #pragma unroll
        for (int off = 32; off; off >>= 1) {
            sc += __shfl_xor(sc, off);
            sm += __shfl_xor(sm, off);
        }
        if (lane == 0) {
            double dc = sqrt(fmax(q2r + c2c[(size_t)b * NN + idx] - 2.0 * sc, 0.0));
            double dm = sqrt(fmax(q2r + c2m[(size_t)b * NN + idx] - 2.0 * sm, 0.0));
            sval[w][c] = g * dc + (1.0 - g) * dm;
            sidx[w][c] = idx;
        }
    }
    // per-wave private LDS rows written and read by the same lane; no barrier
    if (lane == 0) {
        #pragma unroll
        for (int r = 0; r < TOPN; ++r) {
            double bv = sval[w][0]; int bi = sidx[w][0]; int bp = 0;
            for (int c = 1; c < NCAND; ++c) {
                double v = sval[w][c]; int ii = sidx[w][c];
                if (v < bv || (v == bv && ii < bi)) { bv = v; bi = ii; bp = c; }
            }
            sval[w][bp] = INFINITY; sidx[w][bp] = 0x7fffffff;
            out[(size_t)row * TOPN + r] = (float)bv;
            out[(size_t)ROWS * TOPN + (size_t)row * TOPN + r] = (float)bi;
        }
    }
}

extern "C" void kernel_launch(void* const* d_in, const int* in_sizes, int n_in,
                              void* d_out, int out_size, void* d_ws, size_t ws_size,
                              hipStream_t stream)
{
    const float* q   = (const float*)d_in[0];
    const float* ctx = (const float*)d_in[1];
    const float* mem = (const float*)d_in[2];
    const float* Wq  = (const float*)d_in[3];
    const float* bq  = (const float*)d_in[4];
    const float* wg  = (const float*)d_in[5];
    const float* bg  = (const float*)d_in[6];
    float* out = (float*)d_out;

    char* ws = (char*)d_ws;
    double* qp64  = (double*)ws;  ws += (size_t)ROWS * DD * 8;        // 16 MB
    double* q264  = (double*)ws;  ws += (size_t)ROWS * 8;
    double* g64   = (double*)ws;  ws += (size_t)ROWS * 8;
    double* c2c64 = (double*)ws;  ws += (size_t)BB * NN * 8;
    double* c2m64 = (double*)ws;  ws += (size_t)BB * NN * 8;
    unsigned short* qpb  = (unsigned short*)ws; ws += (size_t)ROWS * DD * 2;    // 4 MB
    unsigned short* ctxb = (unsigned short*)ws; ws += (size_t)BB * NN * DD * 2; // 8 MB
    unsigned short* memb = (unsigned short*)ws; ws += (size_t)BB * NN * DD * 2; // 8 MB
    float*  q232  = (float*)ws;   ws += (size_t)ROWS * 4;
    float*  g32   = (float*)ws;   ws += (size_t)ROWS * 4;
    float*  c2c32 = (float*)ws;   ws += (size_t)BB * NN * 4;
    float*  c2m32 = (float*)ws;   ws += (size_t)BB * NN * 4;
    unsigned* distP = (unsigned*)ws; ws += (size_t)(ROWS / 2) * NN * 4;  // 67 MB
    int*    cand  = (int*)ws;     ws += (size_t)ROWS * NCAND * 4;
    unsigned short* cval = (unsigned short*)ws; ws += (size_t)ROWS * NCAND * 2;

    k_proj_prep<<<PROJ_BLKS + PREP_BLKS, 256, 0, stream>>>(
        q, Wq, bq, qp64, qpb, ctx, mem, ctxb, memb,
        c2c64, c2m64, c2c32, c2m32);
    k_row_stats<<<ROWS/4, 256, 0, stream>>>(qp64, q, wg, bg,
                                            q264, q232, g64, g32);
    k_dist_mfma<<<NWG, 256, 0, stream>>>(
        qpb, ctxb, memb, q232, g32, c2c32, c2m32, distP);
    k_filter<<<(ROWS/2)/4, 256, 0, stream>>>(distP, cand, cval);
    k_rescore<<<ROWS/4, 256, 0, stream>>>(qp64, ctx, mem, q264, g64,
                                          c2c64, c2m64, cand, cval, out);
}